// Round 11
// baseline (573.413 us; speedup 1.0000x reference)
//
#include <hip/hip_runtime.h>
#include <hip/hip_bf16.h>
#include <cstddef>

#define NHOP 10
#define NN 200000
#define FF 128
#define HIDD 256
#define CCC 100
#define NEG_SLOPE_C 0.2f

typedef __attribute__((ext_vector_type(8))) short bf16x8;   // 8 bf16 = 4 VGPR
typedef __attribute__((ext_vector_type(4))) short bf16x4;
typedef __attribute__((ext_vector_type(4))) float f32x4;
typedef __attribute__((ext_vector_type(16))) float f32x16;

__device__ __forceinline__ short f2bfs(float x){
  return __builtin_bit_cast(short, __float2bfloat16(x));    // native v_cvt, RNE
}
__device__ __forceinline__ float bf2f(short s){
  return __uint_as_float(((unsigned)(unsigned short)s) << 16);
}
__device__ __forceinline__ f32x4 mfma16(bf16x8 a, bf16x8 b, f32x4 c){
  return __builtin_amdgcn_mfma_f32_16x16x32_bf16(a, b, c, 0, 0, 0);
}
__device__ __forceinline__ f32x16 mfma32(bf16x8 a, bf16x8 b, f32x16 c){
  return __builtin_amdgcn_mfma_f32_32x32x16_bf16(a, b, c, 0, 0, 0);
}
__device__ __forceinline__ float leakyf(float x){ return x >= 0.f ? x : NEG_SLOPE_C*x; }

// ---------------- Kernel 0: weight prep (bf16 + transpose + pad) ----------------
// W1T: [256][128] (col-major-of-original). W2T: [128][256] (pad cols 100..127 = 0).
__global__ __launch_bounds__(256) void prep_weights(
    const float* __restrict__ Wo1, const float* __restrict__ Wl1,
    const float* __restrict__ Wo2, const float* __restrict__ Wl2,
    unsigned short* __restrict__ Wo1T, unsigned short* __restrict__ Wl1T,
    unsigned short* __restrict__ Wo2T, unsigned short* __restrict__ Wl2T)
{
  const int id = blockIdx.x*256 + threadIdx.x;          // 0..32767
  {
    const int c = id >> 7, k = id & 127;                // layout [256][128]
    Wo1T[id] = (unsigned short)f2bfs(Wo1[(size_t)k*HIDD + c]);           // Wo1 [128][256]
    Wl1T[id] = (k < CCC) ? (unsigned short)f2bfs(Wl1[(size_t)k*HIDD + c]) : 0;  // pad k
  }
  {
    const int c = id >> 8, k = id & 255;                // layout [128][256]
    Wo2T[id] = (c < CCC) ? (unsigned short)f2bfs(Wo2[(size_t)k*CCC + c]) : 0;   // pad c
    Wl2T[id] = (c < CCC) ? (unsigned short)f2bfs(Wl2[(size_t)k*CCC + c]) : 0;
  }
}

// ---------------- Kernel 1: hop attention -> right (N x F, bf16) ----------------
// R4/R8-proven attn4, verbatim.
__global__ __launch_bounds__(256) void attn_right_kernel(
    const float* __restrict__ feat,   // H,N,F
    const float* __restrict__ Watt,   // 2F
    const float* __restrict__ batt,   // 1
    unsigned short* __restrict__ rightb)  // N,F bf16
{
  const int lane = threadIdx.x & 63;
  const int w = threadIdx.x >> 6;
  const int nl = lane >> 4, fl = lane & 15;
  const int n = blockIdx.x*16 + w*4 + nl;               // 12500*16 = 200000 exact

  const float4 w1a = *reinterpret_cast<const float4*>(Watt + fl*4);
  const float4 w1b = *reinterpret_cast<const float4*>(Watt + 64 + fl*4);
  const float4 w2a = *reinterpret_cast<const float4*>(Watt + FF + fl*4);
  const float4 w2b = *reinterpret_cast<const float4*>(Watt + FF + 64 + fl*4);
  const float b = batt[0];

  float p1[NHOP], p2[NHOP];
  bf16x8 fbf[NHOP];
  const float* fp = feat + (size_t)n*FF;
  #pragma unroll
  for (int i=0;i<NHOP;i++){
    const float* hp = fp + (size_t)i*((size_t)NN*FF);
    const float4 va = *reinterpret_cast<const float4*>(hp + fl*4);
    const float4 vb = *reinterpret_cast<const float4*>(hp + 64 + fl*4);
    p1[i] = va.x*w1a.x + va.y*w1a.y + va.z*w1a.z + va.w*w1a.w
          + vb.x*w1b.x + vb.y*w1b.y + vb.z*w1b.z + vb.w*w1b.w;
    p2[i] = va.x*w2a.x + va.y*w2a.y + va.z*w2a.z + va.w*w2a.w
          + vb.x*w2b.x + vb.y*w2b.y + vb.z*w2b.z + vb.w*w2b.w;
    fbf[i][0]=f2bfs(va.x); fbf[i][1]=f2bfs(va.y); fbf[i][2]=f2bfs(va.z); fbf[i][3]=f2bfs(va.w);
    fbf[i][4]=f2bfs(vb.x); fbf[i][5]=f2bfs(vb.y); fbf[i][6]=f2bfs(vb.z); fbf[i][7]=f2bfs(vb.w);
  }
  #pragma unroll
  for (int m=8;m>0;m>>=1){
    #pragma unroll
    for (int i=0;i<NHOP;i++){
      p1[i] += __shfl_xor(p1[i], m, 64);
      p2[i] += __shfl_xor(p2[i], m, 64);
    }
  }
  float sc[NHOP];
  sc[0] = leakyf(p1[0] + p2[0] + b);
  #pragma unroll
  for (int i=1;i<NHOP;i++){
    float mx = sc[0];
    #pragma unroll
    for (int j=1;j<i;j++) mx = fmaxf(mx, sc[j]);
    float Z = 0.f, hs = 0.f;
    #pragma unroll
    for (int j=0;j<i;j++){
      const float e = __expf(sc[j]-mx);
      Z += e;
      hs = fmaf(e, p1[j], hs);
    }
    sc[i] = leakyf(hs/Z + p2[i] + b);
  }
  float mx = sc[0];
  #pragma unroll
  for (int j=1;j<NHOP;j++) mx = fmaxf(mx, sc[j]);
  float Z = 0.f;
  float e[NHOP];
  #pragma unroll
  for (int j=0;j<NHOP;j++){ e[j] = __expf(sc[j]-mx); Z += e[j]; }
  const float inv = 1.f/Z;
  float racc[8];
  #pragma unroll
  for (int u=0;u<8;u++) racc[u] = 0.f;
  #pragma unroll
  for (int j=0;j<NHOP;j++){
    const float a = e[j]*inv;
    #pragma unroll
    for (int u=0;u<8;u++) racc[u] = fmaf(a, bf2f(fbf[j][u]), racc[u]);
  }
  bf16x4 sa, sb;
  sa[0]=f2bfs(racc[0]); sa[1]=f2bfs(racc[1]); sa[2]=f2bfs(racc[2]); sa[3]=f2bfs(racc[3]);
  sb[0]=f2bfs(racc[4]); sb[1]=f2bfs(racc[5]); sb[2]=f2bfs(racc[6]); sb[3]=f2bfs(racc[7]);
  *reinterpret_cast<bf16x4*>(rightb + (size_t)n*FF + fl*4) = sa;
  *reinterpret_cast<bf16x4*>(rightb + (size_t)n*FF + 64 + fl*4) = sb;
}

// ---------------- Kernel 2: MFMA MLP (G1 16x16 col-split; G2 32x32 tile-split) ----------------
__device__ __forceinline__ void gemm1_colsplit(
    const unsigned short* sA, unsigned short* sH,
    const unsigned short* __restrict__ W1T, const float* __restrict__ b1, const float alpha,
    const int w, const int lr, const int lq)
{
  bf16x8 B[4][4];
  float b1c[4];
  #pragma unroll
  for (int ctl=0; ctl<4; ++ctl){
    const int c = (4*w+ctl)*16 + lr;
    b1c[ctl] = b1[c];
    #pragma unroll
    for (int kk=0; kk<4; ++kk)
      B[ctl][kk] = *reinterpret_cast<const bf16x8*>(W1T + (size_t)c*128 + kk*32 + lq*8);
  }
  #pragma unroll
  for (int nt=0; nt<4; ++nt){
    f32x4 h[4];
    #pragma unroll
    for (int ctl=0; ctl<4; ++ctl) h[ctl] = (f32x4){0.f,0.f,0.f,0.f};
    const int row = nt*16 + lr;
    #pragma unroll
    for (int kk=0; kk<4; ++kk){
      const bf16x8 a = *reinterpret_cast<const bf16x8*>(
          (const char*)sA + row*256 + ((kk*64 + lq*16) ^ ((row&7)<<4)));
      #pragma unroll
      for (int ctl=0; ctl<4; ++ctl)
        h[ctl] = mfma16(a, B[ctl][kk], h[ctl]);
    }
    #pragma unroll
    for (int ctl=0; ctl<4; ++ctl){
      const int c = (4*w+ctl)*16 + lr;
      #pragma unroll
      for (int j=0; j<4; ++j){
        float v = h[ctl][j] + b1c[ctl];
        v = v >= 0.f ? v : alpha*v;
        const int n = nt*16 + lq*4 + j;
        *reinterpret_cast<unsigned short*>(
            (char*)sH + n*512 + ((2*c) ^ ((n&7)<<4))) = (unsigned short)f2bfs(v);
      }
    }
  }
}

// GEMM2 with 32x32x16 MFMA: wave w -> row-tile (w>>1), col-tiles {2*(w&1), 2*(w&1)+1}.
// A-frags read once per k-half, reused across both col-tiles (16 ds_read/wave/branch).
__device__ __forceinline__ void gemm2_32(const unsigned short* sH,
    const unsigned short* __restrict__ W2T, f32x16 (&o2)[2],
    const int w, const int l31, const int hi)
{
  const int row = (w>>1)*32 + l31;
  const int ctb = (w&1)*2;
  #pragma unroll
  for (int half=0; half<2; ++half){
    bf16x8 a2[8];
    #pragma unroll
    for (int kk=0; kk<8; ++kk){
      const int kidx = (half*8+kk)*16 + hi*8;       // k element index (0..255)
      a2[kk] = *reinterpret_cast<const bf16x8*>(
          (const char*)sH + row*512 + ((2*kidx) ^ ((row&7)<<4)));
    }
    #pragma unroll
    for (int ct=0; ct<2; ++ct){
      const int c = (ctb+ct)*32 + l31;
      #pragma unroll
      for (int kk=0; kk<8; ++kk){
        const bf16x8 b2 = *reinterpret_cast<const bf16x8*>(
            W2T + (size_t)c*256 + (half*8+kk)*16 + hi*8);
        o2[ct] = mfma32(a2[kk], b2, o2[ct]);
      }
    }
  }
}

__global__ __launch_bounds__(256) void mlp_mfma_kernel(
    const unsigned short* __restrict__ rightb, const float* __restrict__ label,
    const unsigned short* __restrict__ Wo1T, const float* __restrict__ bo1, const float* __restrict__ aop,
    const unsigned short* __restrict__ Wo2T, const float* __restrict__ bo2,
    const unsigned short* __restrict__ Wl1T, const float* __restrict__ bl1, const float* __restrict__ alp,
    const unsigned short* __restrict__ Wl2T, const float* __restrict__ bl2,
    float* __restrict__ out)
{
  __shared__ __align__(16) unsigned short sA[64*128];   // 16 KB staged A (swizzled)
  __shared__ __align__(16) unsigned short sH[64*256];   // 32 KB h (swizzled)
  const int t = threadIdx.x;
  const int w = t >> 6, lane = t & 63, lr = lane & 15, lq = lane >> 4;
  const int l31 = lane & 31, hi = lane >> 5;
  const size_t nb = (size_t)blockIdx.x * 64;

  // init 32x32 accumulators with final biases: col = cttile*32 + l31 (same for all regs)
  f32x16 o2[2];
  #pragma unroll
  for (int ct=0; ct<2; ++ct){
    const int c2 = ((w&1)*2+ct)*32 + l31;
    const float init = (c2 < CCC) ? (bo2[c2] + bl2[c2]) : 0.f;
    #pragma unroll
    for (int r=0; r<16; ++r) o2[ct][r] = init;
  }

  // stage right tile (bf16, swizzled)
  {
    const unsigned short* src = rightb + nb*FF;
    #pragma unroll
    for (int i=0;i<4;i++){
      const int chunk = t + 256*i;
      const int row = chunk >> 4, cs = chunk & 15;
      const bf16x8 v = *reinterpret_cast<const bf16x8*>(src + row*FF + cs*8);
      *reinterpret_cast<bf16x8*>((char*)sA + row*256 + ((cs*16) ^ ((row&7)<<4))) = v;
    }
  }
  __syncthreads();                                   // B1: right staged

  gemm1_colsplit(sA, sH, Wo1T, bo1, aop[0], w, lr, lq);
  __syncthreads();                                   // B2: sH(b1) ready; sA free

  // stage label tile into sA (VMEM issued before GEMM2 so latency hides under MFMA)
  {
    #pragma unroll
    for (int i=0;i<7;i++){
      const int idx = t + 256*i;
      if (idx < 1600){
        const int row = idx/25, c0 = (idx%25)*4;
        const float4 v = *reinterpret_cast<const float4*>(label + (nb+row)*CCC + c0);
        bf16x4 p;
        p[0] = f2bfs(v.x); p[1] = f2bfs(v.y);
        p[2] = f2bfs(v.z); p[3] = f2bfs(v.w);
        *reinterpret_cast<bf16x4*>((char*)sA + row*256 + ((2*c0) ^ ((row&7)<<4))) = p;
      }
    }
    for (int idx = t; idx < 448; idx += 256){
      const int row = idx/7, ch = idx%7;
      *reinterpret_cast<bf16x4*>((char*)sA + row*256 + ((200 + 8*ch) ^ ((row&7)<<4))) = (bf16x4){0,0,0,0};
    }
  }
  gemm2_32(sH, Wo2T, o2, w, l31, hi);
  __syncthreads();                                   // B3: label staged; sH(b1) consumed

  gemm1_colsplit(sA, sH, Wl1T, bl1, alp[0], w, lr, lq);
  __syncthreads();                                   // B4: sH(b2) ready
  gemm2_32(sH, Wl2T, o2, w, l31, hi);

  // store out: 32x32 C layout col=l31, row=(reg&3)+8*(reg>>2)+4*hi
  #pragma unroll
  for (int ct=0; ct<2; ++ct){
    const int c2 = ((w&1)*2+ct)*32 + l31;
    if (c2 < CCC){
      #pragma unroll
      for (int r=0; r<16; ++r){
        const int n = (w>>1)*32 + (r&3) + 8*(r>>2) + 4*hi;
        out[(nb + n)*CCC + c2] = o2[ct][r];
      }
    }
  }
}

extern "C" void kernel_launch(void* const* d_in, const int* in_sizes, int n_in,
                              void* d_out, int out_size, void* d_ws, size_t ws_size,
                              hipStream_t stream) {
  const float* feat  = (const float*)d_in[0];
  const float* label = (const float*)d_in[1];
  const float* Watt  = (const float*)d_in[2];
  const float* batt  = (const float*)d_in[3];
  const float* Wo1   = (const float*)d_in[4];
  const float* bo1   = (const float*)d_in[5];
  const float* aop   = (const float*)d_in[6];
  const float* Wo2   = (const float*)d_in[7];
  const float* bo2   = (const float*)d_in[8];
  const float* Wl1   = (const float*)d_in[9];
  const float* bl1   = (const float*)d_in[10];
  const float* alp   = (const float*)d_in[11];
  const float* Wl2   = (const float*)d_in[12];
  const float* bl2   = (const float*)d_in[13];
  float* out = (float*)d_out;

  unsigned short* rightb = (unsigned short*)d_ws;          // N*F bf16 = 51.2 MB
  unsigned short* Wo1T = rightb + (size_t)NN*FF;           // [256][128]
  unsigned short* Wl1T = Wo1T + 256*128;                   // [256][128]
  unsigned short* Wo2T = Wl1T + 256*128;                   // [128][256]
  unsigned short* Wl2T = Wo2T + 128*256;                   // [128][256]

  prep_weights<<<128, 256, 0, stream>>>(Wo1, Wl1, Wo2, Wl2, Wo1T, Wl1T, Wo2T, Wl2T);
  attn_right_kernel<<<NN/16, 256, 0, stream>>>(feat, Watt, batt, rightb);
  // MEASUREMENT: mlp launched TWICE (idempotent -> identical output).
  // mlp_new = T_R11 - 222;  attn4+prep = 222 (from R10).
  mlp_mfma_kernel<<<NN/64, 256, 0, stream>>>(rightb, label,
                                             Wo1T, bo1, aop, Wo2T, bo2,
                                             Wl1T, bl1, alp, Wl2T, bl2, out);
  mlp_mfma_kernel<<<NN/64, 256, 0, stream>>>(rightb, label,
                                             Wo1T, bo1, aop, Wo2T, bo2,
                                             Wl1T, bl1, alp, Wl2T, bl2, out);
}

// Round 12
// 544.208 us; speedup vs baseline: 1.0537x; 1.0537x over previous
//
#include <hip/hip_runtime.h>
#include <hip/hip_bf16.h>
#include <cstddef>

#define NHOP 10
#define NN 200000
#define FF 128
#define HIDD 256
#define CCC 100
#define NEG_SLOPE_C 0.2f

typedef __attribute__((ext_vector_type(8))) short bf16x8;   // 8 bf16 = 4 VGPR
typedef __attribute__((ext_vector_type(4))) short bf16x4;
typedef __attribute__((ext_vector_type(4))) float f32x4;

__device__ __forceinline__ short f2bfs(float x){
  return __builtin_bit_cast(short, __float2bfloat16(x));    // native v_cvt, RNE
}
__device__ __forceinline__ float bf2f(short s){
  return __uint_as_float(((unsigned)(unsigned short)s) << 16);
}
__device__ __forceinline__ f32x4 mfma16(bf16x8 a, bf16x8 b, f32x4 c){
  return __builtin_amdgcn_mfma_f32_16x16x32_bf16(a, b, c, 0, 0, 0);
}
__device__ __forceinline__ float leakyf(float x){ return x >= 0.f ? x : NEG_SLOPE_C*x; }

// ---------------- Kernel 0: weight prep (bf16 + transpose + pad), R8 layouts ----------------
__global__ __launch_bounds__(256) void prep_weights(
    const float* __restrict__ Wo1, const float* __restrict__ Wl1,
    const float* __restrict__ Wo2, const float* __restrict__ Wl2,
    unsigned short* __restrict__ Wo1T, unsigned short* __restrict__ Wl1T,
    unsigned short* __restrict__ Wo2T, unsigned short* __restrict__ Wl2T)
{
  const int id = blockIdx.x*256 + threadIdx.x;          // 0..32767
  {
    const int c = id >> 7, k = id & 127;                // layout [256][128]
    Wo1T[id] = (unsigned short)f2bfs(Wo1[(size_t)k*HIDD + c]);           // Wo1 [128][256]
    Wl1T[id] = (k < CCC) ? (unsigned short)f2bfs(Wl1[(size_t)k*HIDD + c]) : 0;  // pad k
  }
  if (id < 112*256){
    const int c = id >> 8, k = id & 255;                // layout [112][256]
    Wo2T[id] = (c < CCC) ? (unsigned short)f2bfs(Wo2[(size_t)k*CCC + c]) : 0;   // pad c
    Wl2T[id] = (c < CCC) ? (unsigned short)f2bfs(Wl2[(size_t)k*CCC + c]) : 0;
  }
}

// ---------------- MLP helpers, 16-node tile (mlpA bodies specialized to 1 node-tile) ----------
__device__ __forceinline__ void g1_16(
    const unsigned short* sA, unsigned short* sH,
    const unsigned short* __restrict__ W1T, const float* __restrict__ b1, const float alpha,
    const int w, const int lr, const int lq)
{
  bf16x8 B[4][4];
  float b1c[4];
  #pragma unroll
  for (int ctl=0; ctl<4; ++ctl){
    const int c = (4*w+ctl)*16 + lr;
    b1c[ctl] = b1[c];
    #pragma unroll
    for (int kk=0; kk<4; ++kk)
      B[ctl][kk] = *reinterpret_cast<const bf16x8*>(W1T + (size_t)c*128 + kk*32 + lq*8);
  }
  f32x4 h[4];
  #pragma unroll
  for (int ctl=0; ctl<4; ++ctl) h[ctl] = (f32x4){0.f,0.f,0.f,0.f};
  #pragma unroll
  for (int kk=0; kk<4; ++kk){
    const bf16x8 a = *reinterpret_cast<const bf16x8*>(
        (const char*)sA + lr*256 + ((kk*64 + lq*16) ^ ((lr&7)<<4)));
    #pragma unroll
    for (int ctl=0; ctl<4; ++ctl)
      h[ctl] = mfma16(a, B[ctl][kk], h[ctl]);
  }
  #pragma unroll
  for (int ctl=0; ctl<4; ++ctl){
    const int c = (4*w+ctl)*16 + lr;
    #pragma unroll
    for (int j=0; j<4; ++j){
      float v = h[ctl][j] + b1c[ctl];
      v = v >= 0.f ? v : alpha*v;
      const int n = lq*4 + j;
      *reinterpret_cast<unsigned short*>(
          (char*)sH + n*512 + ((2*c) ^ ((n&7)<<4))) = (unsigned short)f2bfs(v);
    }
  }
}

__device__ __forceinline__ void g2_16(const unsigned short* sH,
    const unsigned short* __restrict__ W2T, f32x4 (&o)[2],
    const int w, const int lr, const int lq)
{
  bf16x8 a2[8];
  #pragma unroll
  for (int kk=0; kk<8; ++kk)
    a2[kk] = *reinterpret_cast<const bf16x8*>(
        (const char*)sH + lr*512 + ((kk*64 + lq*16) ^ ((lr&7)<<4)));
  #pragma unroll
  for (int i2=0; i2<2; ++i2){
    const int ct2 = w + 4*i2;
    if (ct2 < 7){
      #pragma unroll
      for (int kk=0; kk<8; ++kk){
        const bf16x8 b2 = *reinterpret_cast<const bf16x8*>(
            W2T + (size_t)(ct2*16+lr)*256 + kk*32 + lq*8);
        o[i2] = mfma16(a2[kk], b2, o[i2]);
      }
    }
  }
}

// ---------------- Fused kernel: 16 nodes/block, attn (1 iter/wave) -> LDS -> MLP ----------------
__global__ __launch_bounds__(256) void gamlp_fused16(
    const float* __restrict__ feat, const float* __restrict__ label,
    const float* __restrict__ Watt, const float* __restrict__ batt,
    const unsigned short* __restrict__ Wo1T, const float* __restrict__ bo1, const float* __restrict__ aop,
    const unsigned short* __restrict__ Wo2T, const float* __restrict__ bo2,
    const unsigned short* __restrict__ Wl1T, const float* __restrict__ bl1, const float* __restrict__ alp,
    const unsigned short* __restrict__ Wl2T, const float* __restrict__ bl2,
    float* __restrict__ out)
{
  __shared__ __align__(16) unsigned short sA[16*128];   // 4 KB: right / label tile (swizzled bf16)
  __shared__ __align__(16) unsigned short sH[16*256];   // 8 KB: h tile (swizzled bf16)
  const int t = threadIdx.x;
  const int w = t >> 6, lane = t & 63;
  const int nl = lane >> 4, fl = lane & 15;             // attn roles
  const int lr = lane & 15, lq = lane >> 4;             // mlp roles
  const size_t nb = (size_t)blockIdx.x * 16;

  // ---------- Phase A: hop attention, ONE iteration per wave (attn4 shape) ----------
  {
    const int n = (int)nb + w*4 + nl;
    const float4 w1a = *reinterpret_cast<const float4*>(Watt + fl*4);
    const float4 w1b = *reinterpret_cast<const float4*>(Watt + 64 + fl*4);
    const float4 w2a = *reinterpret_cast<const float4*>(Watt + FF + fl*4);
    const float4 w2b = *reinterpret_cast<const float4*>(Watt + FF + 64 + fl*4);
    const float b = batt[0];

    float p1[NHOP], p2[NHOP];
    bf16x8 fbf[NHOP];
    const float* fp = feat + (size_t)n*FF;
    #pragma unroll
    for (int i=0;i<NHOP;i++){
      const float* hp = fp + (size_t)i*((size_t)NN*FF);
      const float4 va = *reinterpret_cast<const float4*>(hp + fl*4);
      const float4 vb = *reinterpret_cast<const float4*>(hp + 64 + fl*4);
      p1[i] = va.x*w1a.x + va.y*w1a.y + va.z*w1a.z + va.w*w1a.w
            + vb.x*w1b.x + vb.y*w1b.y + vb.z*w1b.z + vb.w*w1b.w;
      p2[i] = va.x*w2a.x + va.y*w2a.y + va.z*w2a.z + va.w*w2a.w
            + vb.x*w2b.x + vb.y*w2b.y + vb.z*w2b.z + vb.w*w2b.w;
      fbf[i][0]=f2bfs(va.x); fbf[i][1]=f2bfs(va.y); fbf[i][2]=f2bfs(va.z); fbf[i][3]=f2bfs(va.w);
      fbf[i][4]=f2bfs(vb.x); fbf[i][5]=f2bfs(vb.y); fbf[i][6]=f2bfs(vb.z); fbf[i][7]=f2bfs(vb.w);
    }
    #pragma unroll
    for (int m=8;m>0;m>>=1){
      #pragma unroll
      for (int i=0;i<NHOP;i++){
        p1[i] += __shfl_xor(p1[i], m, 64);
        p2[i] += __shfl_xor(p2[i], m, 64);
      }
    }
    float sc[NHOP];
    sc[0] = leakyf(p1[0] + p2[0] + b);
    #pragma unroll
    for (int i=1;i<NHOP;i++){
      float mx = sc[0];
      #pragma unroll
      for (int j=1;j<i;j++) mx = fmaxf(mx, sc[j]);
      float Z = 0.f, hs = 0.f;
      #pragma unroll
      for (int j=0;j<i;j++){
        const float e = __expf(sc[j]-mx);
        Z += e;
        hs = fmaf(e, p1[j], hs);
      }
      sc[i] = leakyf(hs/Z + p2[i] + b);
    }
    float mx = sc[0];
    #pragma unroll
    for (int j=1;j<NHOP;j++) mx = fmaxf(mx, sc[j]);
    float Z = 0.f;
    float e[NHOP];
    #pragma unroll
    for (int j=0;j<NHOP;j++){ e[j] = __expf(sc[j]-mx); Z += e[j]; }
    const float inv = 1.f/Z;
    float racc[8];
    #pragma unroll
    for (int u=0;u<8;u++) racc[u] = 0.f;
    #pragma unroll
    for (int j=0;j<NHOP;j++){
      const float a = e[j]*inv;
      #pragma unroll
      for (int u=0;u<8;u++) racc[u] = fmaf(a, bf2f(fbf[j][u]), racc[u]);
    }
    bf16x4 sa, sb;
    sa[0]=f2bfs(racc[0]); sa[1]=f2bfs(racc[1]); sa[2]=f2bfs(racc[2]); sa[3]=f2bfs(racc[3]);
    sb[0]=f2bfs(racc[4]); sb[1]=f2bfs(racc[5]); sb[2]=f2bfs(racc[6]); sb[3]=f2bfs(racc[7]);
    // right -> LDS (swizzled), row = local node 0..15
    const int row = w*4 + nl;
    *reinterpret_cast<bf16x4*>((char*)sA + row*256 + ((fl*8) ^ ((row&7)<<4))) = sa;
    *reinterpret_cast<bf16x4*>((char*)sA + row*256 + ((128 + fl*8) ^ ((row&7)<<4))) = sb;
  }
  __syncthreads();                                   // B1: right tile in sA

  // init out accumulators with final biases: o[i2] for ct2 = w + 4*i2
  f32x4 o[2];
  #pragma unroll
  for (int i2=0; i2<2; ++i2){
    const int ct2 = w + 4*i2;
    const int c2 = ct2*16 + lr;
    const float init = (ct2 < 7 && c2 < CCC) ? (bo2[c2] + bl2[c2]) : 0.f;
    o[i2] = (f32x4){init, init, init, init};
  }

  g1_16(sA, sH, Wo1T, bo1, aop[0], w, lr, lq);
  __syncthreads();                                   // B2: sH(b1) ready; sA free

  // stage label tile into sA (issued before G2 so HBM latency hides under MFMA)
  {
    for (int idx = t; idx < 400; idx += 256){
      const int row = idx/25, c0 = (idx%25)*4;
      const float4 v = *reinterpret_cast<const float4*>(label + (nb+row)*CCC + c0);
      bf16x4 p;
      p[0] = f2bfs(v.x); p[1] = f2bfs(v.y);
      p[2] = f2bfs(v.z); p[3] = f2bfs(v.w);
      *reinterpret_cast<bf16x4*>((char*)sA + row*256 + ((2*c0) ^ ((row&7)<<4))) = p;
    }
    if (t < 112){
      const int row = t/7, ch = t%7;
      *reinterpret_cast<bf16x4*>((char*)sA + row*256 + ((200 + 8*ch) ^ ((row&7)<<4))) = (bf16x4){0,0,0,0};
    }
  }
  g2_16(sH, Wo2T, o, w, lr, lq);
  __syncthreads();                                   // B3: label staged; sH(b1) consumed

  g1_16(sA, sH, Wl1T, bl1, alp[0], w, lr, lq);
  __syncthreads();                                   // B4: sH(b2) ready
  g2_16(sH, Wl2T, o, w, lr, lq);

  // store out: ct2 = w + 4*i2, rows n = lq*4+j
  #pragma unroll
  for (int i2=0; i2<2; ++i2){
    const int ct2 = w + 4*i2;
    const int c2 = ct2*16 + lr;
    if (ct2 < 7 && c2 < CCC){
      #pragma unroll
      for (int j=0; j<4; ++j){
        const int n = lq*4 + j;
        out[(nb + n)*CCC + c2] = o[i2][j];
      }
    }
  }
}

extern "C" void kernel_launch(void* const* d_in, const int* in_sizes, int n_in,
                              void* d_out, int out_size, void* d_ws, size_t ws_size,
                              hipStream_t stream) {
  const float* feat  = (const float*)d_in[0];
  const float* label = (const float*)d_in[1];
  const float* Watt  = (const float*)d_in[2];
  const float* batt  = (const float*)d_in[3];
  const float* Wo1   = (const float*)d_in[4];
  const float* bo1   = (const float*)d_in[5];
  const float* aop   = (const float*)d_in[6];
  const float* Wo2   = (const float*)d_in[7];
  const float* bo2   = (const float*)d_in[8];
  const float* Wl1   = (const float*)d_in[9];
  const float* bl1   = (const float*)d_in[10];
  const float* alp   = (const float*)d_in[11];
  const float* Wl2   = (const float*)d_in[12];
  const float* bl2   = (const float*)d_in[13];
  float* out = (float*)d_out;

  unsigned short* Wo1T = (unsigned short*)d_ws;            // [256][128]
  unsigned short* Wl1T = Wo1T + 256*128;                   // [256][128]
  unsigned short* Wo2T = Wl1T + 256*128;                   // [112][256]
  unsigned short* Wl2T = Wo2T + 112*256;                   // [112][256]

  prep_weights<<<128, 256, 0, stream>>>(Wo1, Wl1, Wo2, Wl2, Wo1T, Wl1T, Wo2T, Wl2T);
  gamlp_fused16<<<NN/16, 256, 0, stream>>>(feat, label, Watt, batt,
                                           Wo1T, bo1, aop, Wo2T, bo2,
                                           Wl1T, bl1, alp, Wl2T, bl2, out);
}

// Round 14
// 424.984 us; speedup vs baseline: 1.3493x; 1.2805x over previous
//
#include <hip/hip_runtime.h>
#include <hip/hip_bf16.h>
#include <cstddef>

#define NHOP 10
#define NN 200000
#define FF 128
#define HIDD 256
#define CCC 100
#define NEG_SLOPE_C 0.2f

typedef __attribute__((ext_vector_type(8))) short bf16x8;
typedef __attribute__((ext_vector_type(4))) short bf16x4;
typedef __attribute__((ext_vector_type(4))) float f32x4;

__device__ __forceinline__ short f2bfs(float x){
  return __builtin_bit_cast(short, __float2bfloat16(x));
}
__device__ __forceinline__ float bf2f(short s){
  return __uint_as_float(((unsigned)(unsigned short)s) << 16);
}
__device__ __forceinline__ f32x4 mfma16(bf16x8 a, bf16x8 b, f32x4 c){
  return __builtin_amdgcn_mfma_f32_16x16x32_bf16(a, b, c, 0, 0, 0);
}
__device__ __forceinline__ float leakyf(float x){ return x >= 0.f ? x : NEG_SLOPE_C*x; }

// ---------------- Kernel 0: weight prep (bf16 + transpose + pad), R8 layouts ----------------
__global__ __launch_bounds__(256) void prep_weights(
    const float* __restrict__ Wo1, const float* __restrict__ Wl1,
    const float* __restrict__ Wo2, const float* __restrict__ Wl2,
    unsigned short* __restrict__ Wo1T, unsigned short* __restrict__ Wl1T,
    unsigned short* __restrict__ Wo2T, unsigned short* __restrict__ Wl2T)
{
  const int id = blockIdx.x*256 + threadIdx.x;
  {
    const int c = id >> 7, k = id & 127;                // [256][128]
    Wo1T[id] = (unsigned short)f2bfs(Wo1[(size_t)k*HIDD + c]);
    Wl1T[id] = (k < CCC) ? (unsigned short)f2bfs(Wl1[(size_t)k*HIDD + c]) : 0;
  }
  if (id < 112*256){
    const int c = id >> 8, k = id & 255;                // [112][256]
    Wo2T[id] = (c < CCC) ? (unsigned short)f2bfs(Wo2[(size_t)k*CCC + c]) : 0;
    Wl2T[id] = (c < CCC) ? (unsigned short)f2bfs(Wl2[(size_t)k*CCC + c]) : 0;
  }
}

// ---------------- Kernel 1: hop attention -> right (N x F, bf16) — R8 verbatim ----------------
__global__ __launch_bounds__(256) void attn_right_kernel(
    const float* __restrict__ feat,   // H,N,F
    const float* __restrict__ Watt,   // 2F
    const float* __restrict__ batt,   // 1
    unsigned short* __restrict__ rightb)  // N,F bf16
{
  const int lane = threadIdx.x & 63;
  const int w = threadIdx.x >> 6;
  const int nl = lane >> 4, fl = lane & 15;
  const int n = blockIdx.x*16 + w*4 + nl;               // 12500*16 = 200000 exact

  const float4 w1a = *reinterpret_cast<const float4*>(Watt + fl*4);
  const float4 w1b = *reinterpret_cast<const float4*>(Watt + 64 + fl*4);
  const float4 w2a = *reinterpret_cast<const float4*>(Watt + FF + fl*4);
  const float4 w2b = *reinterpret_cast<const float4*>(Watt + FF + 64 + fl*4);
  const float b = batt[0];

  float p1[NHOP], p2[NHOP];
  bf16x8 fbf[NHOP];
  const float* fp = feat + (size_t)n*FF;
  #pragma unroll
  for (int i=0;i<NHOP;i++){
    const float* hp = fp + (size_t)i*((size_t)NN*FF);
    const float4 va = *reinterpret_cast<const float4*>(hp + fl*4);
    const float4 vb = *reinterpret_cast<const float4*>(hp + 64 + fl*4);
    p1[i] = va.x*w1a.x + va.y*w1a.y + va.z*w1a.z + va.w*w1a.w
          + vb.x*w1b.x + vb.y*w1b.y + vb.z*w1b.z + vb.w*w1b.w;
    p2[i] = va.x*w2a.x + va.y*w2a.y + va.z*w2a.z + va.w*w2a.w
          + vb.x*w2b.x + vb.y*w2b.y + vb.z*w2b.z + vb.w*w2b.w;
    fbf[i][0]=f2bfs(va.x); fbf[i][1]=f2bfs(va.y); fbf[i][2]=f2bfs(va.z); fbf[i][3]=f2bfs(va.w);
    fbf[i][4]=f2bfs(vb.x); fbf[i][5]=f2bfs(vb.y); fbf[i][6]=f2bfs(vb.z); fbf[i][7]=f2bfs(vb.w);
  }
  #pragma unroll
  for (int m=8;m>0;m>>=1){
    #pragma unroll
    for (int i=0;i<NHOP;i++){
      p1[i] += __shfl_xor(p1[i], m, 64);
      p2[i] += __shfl_xor(p2[i], m, 64);
    }
  }
  float sc[NHOP];
  sc[0] = leakyf(p1[0] + p2[0] + b);
  #pragma unroll
  for (int i=1;i<NHOP;i++){
    float mx = sc[0];
    #pragma unroll
    for (int j=1;j<i;j++) mx = fmaxf(mx, sc[j]);
    float Z = 0.f, hs = 0.f;
    #pragma unroll
    for (int j=0;j<i;j++){
      const float e = __expf(sc[j]-mx);
      Z += e;
      hs = fmaf(e, p1[j], hs);
    }
    sc[i] = leakyf(hs/Z + p2[i] + b);
  }
  float mx = sc[0];
  #pragma unroll
  for (int j=1;j<NHOP;j++) mx = fmaxf(mx, sc[j]);
  float Z = 0.f;
  float e[NHOP];
  #pragma unroll
  for (int j=0;j<NHOP;j++){ e[j] = __expf(sc[j]-mx); Z += e[j]; }
  const float inv = 1.f/Z;
  float racc[8];
  #pragma unroll
  for (int u=0;u<8;u++) racc[u] = 0.f;
  #pragma unroll
  for (int j=0;j<NHOP;j++){
    const float a = e[j]*inv;
    #pragma unroll
    for (int u=0;u<8;u++) racc[u] = fmaf(a, bf2f(fbf[j][u]), racc[u]);
  }
  bf16x4 sa, sb;
  sa[0]=f2bfs(racc[0]); sa[1]=f2bfs(racc[1]); sa[2]=f2bfs(racc[2]); sa[3]=f2bfs(racc[3]);
  sb[0]=f2bfs(racc[4]); sb[1]=f2bfs(racc[5]); sb[2]=f2bfs(racc[6]); sb[3]=f2bfs(racc[7]);
  *reinterpret_cast<bf16x4*>(rightb + (size_t)n*FF + fl*4) = sa;
  *reinterpret_cast<bf16x4*>(rightb + (size_t)n*FF + 64 + fl*4) = sb;
}

// ---------------- Kernel 2: MFMA MLP, 32-node tile (24 KB LDS -> 4+ blocks/CU) ----------------
__device__ __forceinline__ void g1_32(
    const unsigned short* sA, unsigned short* sH,
    const unsigned short* __restrict__ W1T, const float* __restrict__ b1, const float alpha,
    const int w, const int lr, const int lq)
{
  #pragma unroll
  for (int cc=0; cc<2; ++cc){
    bf16x8 B[2][4];
    float b1c[2];
    #pragma unroll
    for (int ct=0; ct<2; ++ct){
      const int c = (4*w + cc*2 + ct)*16 + lr;
      b1c[ct] = b1[c];
      #pragma unroll
      for (int kk=0; kk<4; ++kk)
        B[ct][kk] = *reinterpret_cast<const bf16x8*>(W1T + (size_t)c*128 + kk*32 + lq*8);
    }
    #pragma unroll
    for (int nt=0; nt<2; ++nt){
      const int row = nt*16 + lr;
      f32x4 h0 = (f32x4){0.f,0.f,0.f,0.f}, h1 = h0;
      #pragma unroll
      for (int kk=0; kk<4; ++kk){
        const bf16x8 a = *reinterpret_cast<const bf16x8*>(
            (const char*)sA + row*256 + ((kk*64 + lq*16) ^ ((row&7)<<4)));
        h0 = mfma16(a, B[0][kk], h0);
        h1 = mfma16(a, B[1][kk], h1);
      }
      #pragma unroll
      for (int ct=0; ct<2; ++ct){
        const int c = (4*w + cc*2 + ct)*16 + lr;
        const f32x4 hv = ct ? h1 : h0;
        #pragma unroll
        for (int j=0; j<4; ++j){
          float v = hv[j] + b1c[ct];
          v = v >= 0.f ? v : alpha*v;
          const int nrow = nt*16 + lq*4 + j;
          *reinterpret_cast<unsigned short*>(
              (char*)sH + nrow*512 + ((2*c) ^ ((nrow&7)<<4))) = (unsigned short)f2bfs(v);
        }
      }
    }
  }
}

__device__ __forceinline__ void g2_32(const unsigned short* sH,
    const unsigned short* __restrict__ W2T, f32x4 (&o)[2][2],
    const int w, const int lr, const int lq)
{
  bf16x8 a2[2][8];
  #pragma unroll
  for (int nt=0; nt<2; ++nt){
    const int row = nt*16 + lr;
    #pragma unroll
    for (int kk=0; kk<8; ++kk)
      a2[nt][kk] = *reinterpret_cast<const bf16x8*>(
          (const char*)sH + row*512 + ((kk*64 + lq*16) ^ ((row&7)<<4)));
  }
  #pragma unroll
  for (int i2=0; i2<2; ++i2){
    const int ct2 = 2*w + i2;
    if (ct2 < 7){
      #pragma unroll
      for (int kk=0; kk<8; ++kk){
        const bf16x8 b2 = *reinterpret_cast<const bf16x8*>(
            W2T + (size_t)(ct2*16+lr)*256 + kk*32 + lq*8);
        o[i2][0] = mfma16(a2[0][kk], b2, o[i2][0]);
        o[i2][1] = mfma16(a2[1][kk], b2, o[i2][1]);
      }
    }
  }
}

__global__ __launch_bounds__(256) void mlp_mfma32_kernel(
    const unsigned short* __restrict__ rightb, const float* __restrict__ label,
    const unsigned short* __restrict__ Wo1T, const float* __restrict__ bo1, const float* __restrict__ aop,
    const unsigned short* __restrict__ Wo2T, const float* __restrict__ bo2,
    const unsigned short* __restrict__ Wl1T, const float* __restrict__ bl1, const float* __restrict__ alp,
    const unsigned short* __restrict__ Wl2T, const float* __restrict__ bl2,
    float* __restrict__ out)
{
  __shared__ __align__(16) unsigned short sA[32*128];   // 8 KB
  __shared__ __align__(16) unsigned short sH[32*256];   // 16 KB
  const int t = threadIdx.x;
  const int w = t >> 6, lane = t & 63, lr = lane & 15, lq = lane >> 4;
  const size_t nb = (size_t)blockIdx.x * 32;
  const float ao = aop[0], al = alp[0];

  f32x4 o[2][2];
  #pragma unroll
  for (int i2=0; i2<2; ++i2){
    const int ct2 = 2*w + i2;
    const int c2 = ct2*16 + lr;
    const float init = (ct2 < 7 && c2 < CCC) ? (bo2[c2] + bl2[c2]) : 0.f;
    o[i2][0] = (f32x4){init, init, init, init};
    o[i2][1] = o[i2][0];
  }

  // stage right tile (32 x 128 bf16, swizzled)
  {
    const unsigned short* src = rightb + nb*FF;
    #pragma unroll
    for (int i=0;i<2;i++){
      const int chunk = t + 256*i;
      const int row = chunk >> 4, cs = chunk & 15;
      const bf16x8 v = *reinterpret_cast<const bf16x8*>(src + row*FF + cs*8);
      *reinterpret_cast<bf16x8*>((char*)sA + row*256 + ((cs*16) ^ ((row&7)<<4))) = v;
    }
  }
  __syncthreads();                                   // B1

  g1_32(sA, sH, Wo1T, bo1, ao, w, lr, lq);
  __syncthreads();                                   // B2: sH(b1) ready; sA free

  // stage label (32 x 100 fp32 -> bf16, swizzled, pad 100..127) before G2
  {
    for (int idx = t; idx < 800; idx += 256){
      const int row = idx/25, c0 = (idx%25)*4;
      const float4 v = *reinterpret_cast<const float4*>(label + (nb+row)*CCC + c0);
      bf16x4 p;
      p[0] = f2bfs(v.x); p[1] = f2bfs(v.y);
      p[2] = f2bfs(v.z); p[3] = f2bfs(v.w);
      *reinterpret_cast<bf16x4*>((char*)sA + row*256 + ((2*c0) ^ ((row&7)<<4))) = p;
    }
    if (t < 224){
      const int row = t/7, ch = t%7;
      *reinterpret_cast<bf16x4*>((char*)sA + row*256 + ((200 + 8*ch) ^ ((row&7)<<4))) = (bf16x4){0,0,0,0};
    }
  }
  g2_32(sH, Wo2T, o, w, lr, lq);
  __syncthreads();                                   // B3: label staged; sH(b1) consumed

  g1_32(sA, sH, Wl1T, bl1, al, w, lr, lq);
  __syncthreads();                                   // B4
  g2_32(sH, Wl2T, o, w, lr, lq);

  #pragma unroll
  for (int i2=0; i2<2; ++i2){
    const int ct2 = 2*w + i2;
    const int c2 = ct2*16 + lr;
    if (ct2 < 7 && c2 < CCC){
      #pragma unroll
      for (int nt=0; nt<2; ++nt){
        #pragma unroll
        for (int j=0; j<4; ++j){
          const int n = nt*16 + lq*4 + j;
          out[(nb + n)*CCC + c2] = o[i2][nt][j];
        }
      }
    }
  }
}

extern "C" void kernel_launch(void* const* d_in, const int* in_sizes, int n_in,
                              void* d_out, int out_size, void* d_ws, size_t ws_size,
                              hipStream_t stream) {
  const float* feat  = (const float*)d_in[0];
  const float* label = (const float*)d_in[1];
  const float* Watt  = (const float*)d_in[2];
  const float* batt  = (const float*)d_in[3];
  const float* Wo1   = (const float*)d_in[4];
  const float* bo1   = (const float*)d_in[5];
  const float* aop   = (const float*)d_in[6];
  const float* Wo2   = (const float*)d_in[7];
  const float* bo2   = (const float*)d_in[8];
  const float* Wl1   = (const float*)d_in[9];
  const float* bl1   = (const float*)d_in[10];
  const float* alp   = (const float*)d_in[11];
  const float* Wl2   = (const float*)d_in[12];
  const float* bl2   = (const float*)d_in[13];
  float* out = (float*)d_out;

  unsigned short* rightb = (unsigned short*)d_ws;          // N*F bf16 = 51.2 MB
  unsigned short* Wo1T = rightb + (size_t)NN*FF;           // [256][128]
  unsigned short* Wl1T = Wo1T + 256*128;                   // [256][128]
  unsigned short* Wo2T = Wl1T + 256*128;                   // [112][256]
  unsigned short* Wl2T = Wo2T + 112*256;                   // [112][256]

  prep_weights<<<128, 256, 0, stream>>>(Wo1, Wl1, Wo2, Wl2, Wo1T, Wl1T, Wo2T, Wl2T);
  attn_right_kernel<<<NN/16, 256, 0, stream>>>(feat, Watt, batt, rightb);
  mlp_mfma32_kernel<<<NN/32, 256, 0, stream>>>(rightb, label,
                                               Wo1T, bo1, aop, Wo2T, bo2,
                                               Wl1T, bl1, alp, Wl2T, bl2, out);
}

// Round 15
// 347.753 us; speedup vs baseline: 1.6489x; 1.2221x over previous
//
#include <hip/hip_runtime.h>
#include <hip/hip_bf16.h>
#include <cstddef>

#define NHOP 10
#define NN 200000
#define FF 128
#define HIDD 256
#define CCC 100
#define NEG_SLOPE_C 0.2f

typedef __attribute__((ext_vector_type(8))) short bf16x8;
typedef __attribute__((ext_vector_type(4))) short bf16x4;
typedef __attribute__((ext_vector_type(4))) float f32x4;

__device__ __forceinline__ short f2bfs(float x){
  return __builtin_bit_cast(short, __float2bfloat16(x));    // native v_cvt, RNE
}
__device__ __forceinline__ float bf2f(short s){
  return __uint_as_float(((unsigned)(unsigned short)s) << 16);
}
__device__ __forceinline__ f32x4 mfma16(bf16x8 a, bf16x8 b, f32x4 c){
  return __builtin_amdgcn_mfma_f32_16x16x32_bf16(a, b, c, 0, 0, 0);
}
__device__ __forceinline__ float leakyf(float x){ return x >= 0.f ? x : NEG_SLOPE_C*x; }

// ---------------- Kernel 0: weight prep (bf16 + transpose + pad) ----------------
__global__ __launch_bounds__(256) void prep_weights(
    const float* __restrict__ Wo1, const float* __restrict__ Wl1,
    const float* __restrict__ Wo2, const float* __restrict__ Wl2,
    unsigned short* __restrict__ Wo1T, unsigned short* __restrict__ Wl1T,
    unsigned short* __restrict__ Wo2T, unsigned short* __restrict__ Wl2T)
{
  const int id = blockIdx.x*256 + threadIdx.x;
  {
    const int c = id >> 7, k = id & 127;                // [256][128]
    Wo1T[id] = (unsigned short)f2bfs(Wo1[(size_t)k*HIDD + c]);
    Wl1T[id] = (k < CCC) ? (unsigned short)f2bfs(Wl1[(size_t)k*HIDD + c]) : 0;
  }
  if (id < 112*256){
    const int c = id >> 8, k = id & 255;                // [112][256]
    Wo2T[id] = (c < CCC) ? (unsigned short)f2bfs(Wo2[(size_t)k*CCC + c]) : 0;
    Wl2T[id] = (c < CCC) ? (unsigned short)f2bfs(Wl2[(size_t)k*CCC + c]) : 0;
  }
}

// ---------------- Kernel 1: hop attention -> right (N x F, bf16) — R8 verbatim ----------------
__global__ __launch_bounds__(256) void attn_right_kernel(
    const float* __restrict__ feat,   // H,N,F
    const float* __restrict__ Watt,   // 2F
    const float* __restrict__ batt,   // 1
    unsigned short* __restrict__ rightb)  // N,F bf16
{
  const int lane = threadIdx.x & 63;
  const int w = threadIdx.x >> 6;
  const int nl = lane >> 4, fl = lane & 15;
  const int n = blockIdx.x*16 + w*4 + nl;               // 12500*16 = 200000 exact

  const float4 w1a = *reinterpret_cast<const float4*>(Watt + fl*4);
  const float4 w1b = *reinterpret_cast<const float4*>(Watt + 64 + fl*4);
  const float4 w2a = *reinterpret_cast<const float4*>(Watt + FF + fl*4);
  const float4 w2b = *reinterpret_cast<const float4*>(Watt + FF + 64 + fl*4);
  const float b = batt[0];

  float p1[NHOP], p2[NHOP];
  bf16x8 fbf[NHOP];
  const float* fp = feat + (size_t)n*FF;
  #pragma unroll
  for (int i=0;i<NHOP;i++){
    const float* hp = fp + (size_t)i*((size_t)NN*FF);
    const float4 va = *reinterpret_cast<const float4*>(hp + fl*4);
    const float4 vb = *reinterpret_cast<const float4*>(hp + 64 + fl*4);
    p1[i] = va.x*w1a.x + va.y*w1a.y + va.z*w1a.z + va.w*w1a.w
          + vb.x*w1b.x + vb.y*w1b.y + vb.z*w1b.z + vb.w*w1b.w;
    p2[i] = va.x*w2a.x + va.y*w2a.y + va.z*w2a.z + va.w*w2a.w
          + vb.x*w2b.x + vb.y*w2b.y + vb.z*w2b.z + vb.w*w2b.w;
    fbf[i][0]=f2bfs(va.x); fbf[i][1]=f2bfs(va.y); fbf[i][2]=f2bfs(va.z); fbf[i][3]=f2bfs(va.w);
    fbf[i][4]=f2bfs(vb.x); fbf[i][5]=f2bfs(vb.y); fbf[i][6]=f2bfs(vb.z); fbf[i][7]=f2bfs(vb.w);
  }
  #pragma unroll
  for (int m=8;m>0;m>>=1){
    #pragma unroll
    for (int i=0;i<NHOP;i++){
      p1[i] += __shfl_xor(p1[i], m, 64);
      p2[i] += __shfl_xor(p2[i], m, 64);
    }
  }
  float sc[NHOP];
  sc[0] = leakyf(p1[0] + p2[0] + b);
  #pragma unroll
  for (int i=1;i<NHOP;i++){
    float mx = sc[0];
    #pragma unroll
    for (int j=1;j<i;j++) mx = fmaxf(mx, sc[j]);
    float Z = 0.f, hs = 0.f;
    #pragma unroll
    for (int j=0;j<i;j++){
      const float e = __expf(sc[j]-mx);
      Z += e;
      hs = fmaf(e, p1[j], hs);
    }
    sc[i] = leakyf(hs/Z + p2[i] + b);
  }
  float mx = sc[0];
  #pragma unroll
  for (int j=1;j<NHOP;j++) mx = fmaxf(mx, sc[j]);
  float Z = 0.f;
  float e[NHOP];
  #pragma unroll
  for (int j=0;j<NHOP;j++){ e[j] = __expf(sc[j]-mx); Z += e[j]; }
  const float inv = 1.f/Z;
  float racc[8];
  #pragma unroll
  for (int u=0;u<8;u++) racc[u] = 0.f;
  #pragma unroll
  for (int j=0;j<NHOP;j++){
    const float a = e[j]*inv;
    #pragma unroll
    for (int u=0;u<8;u++) racc[u] = fmaf(a, bf2f(fbf[j][u]), racc[u]);
  }
  bf16x4 sa, sb;
  sa[0]=f2bfs(racc[0]); sa[1]=f2bfs(racc[1]); sa[2]=f2bfs(racc[2]); sa[3]=f2bfs(racc[3]);
  sb[0]=f2bfs(racc[4]); sb[1]=f2bfs(racc[5]); sb[2]=f2bfs(racc[6]); sb[3]=f2bfs(racc[7]);
  *reinterpret_cast<bf16x4*>(rightb + (size_t)n*FF + fl*4) = sa;
  *reinterpret_cast<bf16x4*>(rightb + (size_t)n*FF + 64 + fl*4) = sb;
}

// ---------------- Kernel 2: MFMA MLP (R8 mlpA + a2-hoist in GEMM2 only) ----------------
__device__ __forceinline__ void mlp_branch(
    const unsigned short* sA, unsigned short* sH,
    const unsigned short* __restrict__ W1T, const float* __restrict__ b1, const float alpha,
    const unsigned short* __restrict__ W2T,
    f32x4 (&o)[2][4], const int w, const int lr, const int lq)
{
  // ---- GEMM1: [64 x 128] @ [128 x 256] -> h (prelu, bf16 to LDS) — R8 verbatim ----
  bf16x8 B[4][4];
  float b1c[4];
  #pragma unroll
  for (int ctl=0; ctl<4; ++ctl){
    const int c = (4*w+ctl)*16 + lr;
    b1c[ctl] = b1[c];
    #pragma unroll
    for (int kk=0; kk<4; ++kk)
      B[ctl][kk] = *reinterpret_cast<const bf16x8*>(W1T + (size_t)c*128 + kk*32 + lq*8);
  }
  #pragma unroll
  for (int nt=0; nt<4; ++nt){
    f32x4 h[4];
    #pragma unroll
    for (int ctl=0; ctl<4; ++ctl) h[ctl] = (f32x4){0.f,0.f,0.f,0.f};
    const int row = nt*16 + lr;
    #pragma unroll
    for (int kk=0; kk<4; ++kk){
      const bf16x8 a = *reinterpret_cast<const bf16x8*>(
          (const char*)sA + row*256 + ((kk*64 + lq*16) ^ ((row&7)<<4)));
      #pragma unroll
      for (int ctl=0; ctl<4; ++ctl)
        h[ctl] = mfma16(a, B[ctl][kk], h[ctl]);
    }
    #pragma unroll
    for (int ctl=0; ctl<4; ++ctl){
      const int c = (4*w+ctl)*16 + lr;
      #pragma unroll
      for (int j=0; j<4; ++j){
        float v = h[ctl][j] + b1c[ctl];
        v = v >= 0.f ? v : alpha*v;
        const int n = nt*16 + lq*4 + j;
        *reinterpret_cast<unsigned short*>(
            (char*)sH + n*512 + ((2*c) ^ ((n&7)<<4))) = (unsigned short)f2bfs(v);
      }
    }
  }
  __syncthreads();   // h complete (cross-wave rows)
  // ---- GEMM2 (a2-hoist): b2 hoisted, each A-frag read ONCE, reused across both col-tiles ----
  bf16x8 b2[2][8];
  #pragma unroll
  for (int i2=0; i2<2; ++i2){
    const int ct2 = 2*w + i2;
    if (ct2 < 7){
      #pragma unroll
      for (int kk=0; kk<8; ++kk)
        b2[i2][kk] = *reinterpret_cast<const bf16x8*>(W2T + (size_t)(ct2*16+lr)*256 + kk*32 + lq*8);
    }
  }
  #pragma unroll
  for (int nt=0; nt<4; ++nt){
    const int row = nt*16 + lr;
    bf16x8 a2[8];
    #pragma unroll
    for (int kk=0; kk<8; ++kk)
      a2[kk] = *reinterpret_cast<const bf16x8*>(
          (const char*)sH + row*512 + ((kk*64 + lq*16) ^ ((row&7)<<4)));
    #pragma unroll
    for (int i2=0; i2<2; ++i2){
      if (2*w + i2 < 7){
        #pragma unroll
        for (int kk=0; kk<8; ++kk)
          o[i2][nt] = mfma16(a2[kk], b2[i2][kk], o[i2][nt]);
      }
    }
  }
}

__global__ __launch_bounds__(256) void mlp_mfma_kernel(
    const unsigned short* __restrict__ rightb, const float* __restrict__ label,
    const unsigned short* __restrict__ Wo1T, const float* __restrict__ bo1, const float* __restrict__ aop,
    const unsigned short* __restrict__ Wo2T, const float* __restrict__ bo2,
    const unsigned short* __restrict__ Wl1T, const float* __restrict__ bl1, const float* __restrict__ alp,
    const unsigned short* __restrict__ Wl2T, const float* __restrict__ bl2,
    float* __restrict__ out)
{
  __shared__ __align__(16) unsigned short sA[64*128];   // 16 KB staged A (swizzled)
  __shared__ __align__(16) unsigned short sH[64*256];   // 32 KB h (swizzled)
  const int t = threadIdx.x;
  const int w = t >> 6, lane = t & 63, lr = lane & 15, lq = lane >> 4;
  const size_t nb = (size_t)blockIdx.x * 64;

  // init out accumulators with final biases
  f32x4 o[2][4];
  #pragma unroll
  for (int i2=0; i2<2; ++i2){
    const int ct2 = 2*w + i2;
    const int c2 = ct2*16 + lr;
    const float init = (ct2 < 7 && c2 < CCC) ? (bo2[c2] + bl2[c2]) : 0.f;
    #pragma unroll
    for (int nt=0; nt<4; ++nt) o[i2][nt] = (f32x4){init, init, init, init};
  }

  // stage right tile (bf16, swizzled)
  {
    const unsigned short* src = rightb + nb*FF;
    #pragma unroll
    for (int i=0;i<4;i++){
      const int chunk = t + 256*i;
      const int row = chunk >> 4, cs = chunk & 15;
      const bf16x8 v = *reinterpret_cast<const bf16x8*>(src + row*FF + cs*8);
      *reinterpret_cast<bf16x8*>((char*)sA + row*256 + ((cs*16) ^ ((row&7)<<4))) = v;
    }
  }
  __syncthreads();
  mlp_branch(sA, sH, Wo1T, bo1, aop[0], Wo2T, o, w, lr, lq);

  // stage label tile (fp32 -> bf16, swizzled, zero-pad cols 100..127)
  {
    #pragma unroll
    for (int i=0;i<7;i++){
      const int idx = t + 256*i;
      if (idx < 1600){
        const int row = idx/25, c0 = (idx%25)*4;
        const float4 v = *reinterpret_cast<const float4*>(label + (nb+row)*CCC + c0);
        bf16x4 p;
        p[0] = f2bfs(v.x); p[1] = f2bfs(v.y);
        p[2] = f2bfs(v.z); p[3] = f2bfs(v.w);
        *reinterpret_cast<bf16x4*>((char*)sA + row*256 + ((2*c0) ^ ((row&7)<<4))) = p;
      }
    }
    for (int idx = t; idx < 448; idx += 256){
      const int row = idx/7, ch = idx%7;
      *reinterpret_cast<bf16x4*>((char*)sA + row*256 + ((200 + 8*ch) ^ ((row&7)<<4))) = (bf16x4){0,0,0,0};
    }
  }
  __syncthreads();   // also guarantees all waves done reading sH of branch 1
  mlp_branch(sA, sH, Wl1T, bl1, alp[0], Wl2T, o, w, lr, lq);

  // store out (scattered dwords; 16-consecutive-float segments per lane group)
  #pragma unroll
  for (int i2=0; i2<2; ++i2){
    const int ct2 = 2*w + i2;
    const int c2 = ct2*16 + lr;
    if (ct2 < 7 && c2 < CCC){
      #pragma unroll
      for (int nt=0; nt<4; ++nt){
        #pragma unroll
        for (int j=0; j<4; ++j){
          const int n = nt*16 + lq*4 + j;
          out[(nb + n)*CCC + c2] = o[i2][nt][j];
        }
      }
    }
  }
}

extern "C" void kernel_launch(void* const* d_in, const int* in_sizes, int n_in,
                              void* d_out, int out_size, void* d_ws, size_t ws_size,
                              hipStream_t stream) {
  const float* feat  = (const float*)d_in[0];
  const float* label = (const float*)d_in[1];
  const float* Watt  = (const float*)d_in[2];
  const float* batt  = (const float*)d_in[3];
  const float* Wo1   = (const float*)d_in[4];
  const float* bo1   = (const float*)d_in[5];
  const float* aop   = (const float*)d_in[6];
  const float* Wo2   = (const float*)d_in[7];
  const float* bo2   = (const float*)d_in[8];
  const float* Wl1   = (const float*)d_in[9];
  const float* bl1   = (const float*)d_in[10];
  const float* alp   = (const float*)d_in[11];
  const float* Wl2   = (const float*)d_in[12];
  const float* bl2   = (const float*)d_in[13];
  float* out = (float*)d_out;

  unsigned short* rightb = (unsigned short*)d_ws;          // N*F bf16 = 51.2 MB
  unsigned short* Wo1T = rightb + (size_t)NN*FF;           // [256][128]
  unsigned short* Wl1T = Wo1T + 256*128;                   // [256][128]
  unsigned short* Wo2T = Wl1T + 256*128;                   // [112][256]
  unsigned short* Wl2T = Wo2T + 112*256;                   // [112][256]

  prep_weights<<<128, 256, 0, stream>>>(Wo1, Wl1, Wo2, Wl2, Wo1T, Wl1T, Wo2T, Wl2T);
  attn_right_kernel<<<NN/16, 256, 0, stream>>>(feat, Watt, batt, rightb);
  mlp_mfma_kernel<<<NN/64, 256, 0, stream>>>(rightb, label,
                                             Wo1T, bo1, aop, Wo2T, bo2,
                                             Wl1T, bl1, alp, Wl2T, bl2, out);
}